// Round 12
// baseline (94.363 us; speedup 1.0000x reference)
//
#include <hip/hip_runtime.h>
#include <hip/hip_bf16.h>

// SpikingPolicyNet: B=8192, D_in=256, H=1024, D_out=64, T=15, TAU=20, V_TH=1
//
// Pipeline:
//  K0 : W2 -> W2cb (bf16 W2^T, row 1024 zeroed = sentinel for padded entries)
//  K1 : bf16-MFMA x@W1.T; epilogue folds b1 and emits the closed-form spike
//       interval k = ceil(log2(1-1/I)/log2(0.95)) as byte plane kb[b][j]
//       (layer-1 spikes at t = k,2k,...; I1 time-invariant).
//  K2 : block-per-row. LDS bucket-sort by k (buckets padded to x4 with the
//       zero-row sentinel -> quads never straddle buckets). ONE fused quad
//       loop: prefetch quad q+1 (entries + 4 weight loads) before consuming
//       quad q; target G8..G15 / Ps selected by a wave-uniform scalar-branch
//       tree on 4q vs stt[] (static register targets, s_cbranch only).
//       Certificate: M = b2 + Ps + relu(max G8..15) >= max_t I2_t
//       (t<=7: I2 <= b2+Ps; t>=8: t's only divisor >=8 is t). M<=0.999
//       (margin >> fp drift) + induction v2_t <= M(1-.95^t) proves zero s2
//       spikes -> out = bout bit-exact (absmax==0 R1-R11 incl fp32 R1).
//       Cert-failing rows (rare) run the exact per-step re-gather inline.

#define B_SZ   8192
#define D_IN   256
#define H_SZ   1024
#define D_OUT  64
#define T_STEPS 15
#define SKIP_THR 0.999f

typedef __attribute__((ext_vector_type(8))) short short8;
typedef __attribute__((ext_vector_type(4))) float f32x4;

static __device__ __forceinline__ unsigned int pk_bf16(float lo, float hi) {
    return (__builtin_bit_cast(unsigned int, hi) & 0xffff0000u) |
           (__builtin_bit_cast(unsigned int, lo) >> 16);
}
static __device__ __forceinline__ f32x4 unp4(uint2 w) {
    f32x4 r;
    r.x = __builtin_bit_cast(float, w.x << 16);
    r.y = __builtin_bit_cast(float, w.x & 0xffff0000u);
    r.z = __builtin_bit_cast(float, w.y << 16);
    r.w = __builtin_bit_cast(float, w.y & 0xffff0000u);
    return r;
}
static __device__ __forceinline__ f32x4 relu4(f32x4 a) {
    a.x = fmaxf(a.x, 0.f); a.y = fmaxf(a.y, 0.f);
    a.z = fmaxf(a.z, 0.f); a.w = fmaxf(a.w, 0.f);
    return a;
}
static __device__ __forceinline__ f32x4 vmax4(f32x4 a, f32x4 b) {
    f32x4 r;
    r.x = fmaxf(a.x, b.x); r.y = fmaxf(a.y, b.y);
    r.z = fmaxf(a.z, b.z); r.w = fmaxf(a.w, b.w);
    return r;
}

// ---------------------------------------------------------------- K0: W2 -> W2cb (+zero pad row)
__global__ __launch_bounds__(256) void k0_transpose(const float* __restrict__ W2,
                                                    unsigned short* __restrict__ W2cb) {
    __shared__ float tile[32][33];
    const int bx = blockIdx.x * 32;
    const int by = blockIdx.y * 32;
    const int tx = threadIdx.x;
    const int ty = threadIdx.y;
    #pragma unroll
    for (int i = ty; i < 32; i += 8)
        tile[i][tx] = W2[(by + i) * H_SZ + bx + tx];
    __syncthreads();
    #pragma unroll
    for (int i = ty; i < 32; i += 8)
        W2cb[(size_t)(bx + i) * H_SZ + by + tx] =
            (unsigned short)(__builtin_bit_cast(unsigned int, tile[tx][i]) >> 16);
    if (blockIdx.x == 0 && blockIdx.y == 0) {                   // zero sentinel row 1024
        const int t = ty * 32 + tx;
        #pragma unroll
        for (int i = 0; i < 4; ++i)
            W2cb[(size_t)H_SZ * H_SZ + i * 256 + t] = 0;
    }
}

// ---------------------------------------------------------------- K1: interval byte-plane from x@W1.T+b1
__global__ __launch_bounds__(256) void k1_mfma(const float* __restrict__ A,
                                               const float* __restrict__ Bw,
                                               const float* __restrict__ b1,
                                               unsigned char* __restrict__ kb) {
    __shared__ unsigned int As4[2048];   // 128 rows x 32 bf16, 16B-chunk XOR swizzle
    __shared__ unsigned int Bs4[2048];
    const int tid  = threadIdx.x;
    const int m0   = blockIdx.x * 128;
    const int n0   = blockIdx.y * 128;
    const int lane = tid & 63;
    const int wid  = tid >> 6;
    const int wr   = wid >> 1, wc = wid & 1;

    const int row0 = tid >> 2;
    const int row1 = row0 + 64;
    const int q0   = tid & 3;

    f32x4 acc[4][4] = {};
    float4 s0[8], s1[8];

    auto LOAD = [&](float4* s, int kbk) {
        const float* pa0 = A  + (m0 + row0) * D_IN + kbk + q0 * 8;
        const float* pa1 = A  + (m0 + row1) * D_IN + kbk + q0 * 8;
        const float* pb0 = Bw + (n0 + row0) * D_IN + kbk + q0 * 8;
        const float* pb1 = Bw + (n0 + row1) * D_IN + kbk + q0 * 8;
        s[0] = *(const float4*)pa0; s[1] = *(const float4*)(pa0 + 4);
        s[2] = *(const float4*)pa1; s[3] = *(const float4*)(pa1 + 4);
        s[4] = *(const float4*)pb0; s[5] = *(const float4*)(pb0 + 4);
        s[6] = *(const float4*)pb1; s[7] = *(const float4*)(pb1 + 4);
    };
    auto WRITE = [&](const float4* s) {
        const int i0 = row0 * 16 + (q0 ^ ((row0 >> 1) & 3)) * 4;
        const int i1 = row1 * 16 + (q0 ^ ((row1 >> 1) & 3)) * 4;
        *(uint4*)&As4[i0] = make_uint4(pk_bf16(s[0].x, s[0].y), pk_bf16(s[0].z, s[0].w),
                                       pk_bf16(s[1].x, s[1].y), pk_bf16(s[1].z, s[1].w));
        *(uint4*)&As4[i1] = make_uint4(pk_bf16(s[2].x, s[2].y), pk_bf16(s[2].z, s[2].w),
                                       pk_bf16(s[3].x, s[3].y), pk_bf16(s[3].z, s[3].w));
        *(uint4*)&Bs4[i0] = make_uint4(pk_bf16(s[4].x, s[4].y), pk_bf16(s[4].z, s[4].w),
                                       pk_bf16(s[5].x, s[5].y), pk_bf16(s[5].z, s[5].w));
        *(uint4*)&Bs4[i1] = make_uint4(pk_bf16(s[6].x, s[6].y), pk_bf16(s[6].z, s[6].w),
                                       pk_bf16(s[7].x, s[7].y), pk_bf16(s[7].z, s[7].w));
    };
    auto COMPUTE = [&]() {
        short8 afr[4], bfr[4];
        const int q  = lane >> 4;
        const int lr = lane & 15;
        #pragma unroll
        for (int mf = 0; mf < 4; ++mf) {
            const int ra = wr * 64 + mf * 16 + lr;
            afr[mf] = *(const short8*)&As4[ra * 16 + (q ^ ((ra >> 1) & 3)) * 4];
            const int rb = wc * 64 + mf * 16 + lr;
            bfr[mf] = *(const short8*)&Bs4[rb * 16 + (q ^ ((rb >> 1) & 3)) * 4];
        }
        #pragma unroll
        for (int mf = 0; mf < 4; ++mf)
            #pragma unroll
            for (int nf = 0; nf < 4; ++nf)
                acc[mf][nf] = __builtin_amdgcn_mfma_f32_16x16x32_bf16(
                    afr[mf], bfr[nf], acc[mf][nf], 0, 0, 0);
    };

    LOAD(s0, 0);
    for (int kk = 0; kk < D_IN; kk += 64) {
        if (kk + 32 < D_IN) LOAD(s1, kk + 32);
        __syncthreads();
        WRITE(s0);
        __syncthreads();
        COMPUTE();
        if (kk + 64 < D_IN) LOAD(s0, kk + 64);
        __syncthreads();
        WRITE(s1);
        __syncthreads();
        COMPUTE();
    }

    // Epilogue: I = acc + b1[col]; k = ceil(log2(1-1/I)*-13.5134035), 0 = none.
    const int lr = lane & 15;
    const int qq = lane >> 4;
    float b1v[4];
    #pragma unroll
    for (int nf = 0; nf < 4; ++nf) b1v[nf] = b1[n0 + wc * 64 + nf * 16 + lr];

    #pragma unroll
    for (int mf = 0; mf < 4; ++mf) {
        const int rbase = m0 + wr * 64 + mf * 16 + qq * 4;
        #pragma unroll
        for (int nf = 0; nf < 4; ++nf) {
            const int c = n0 + wc * 64 + nf * 16 + lr;
            #pragma unroll
            for (int r = 0; r < 4; ++r) {
                const float I = acc[mf][nf][r] + b1v[nf];
                int k = 0;
                if (I > 1.8632055f) {
                    const float l2 = __builtin_amdgcn_logf(1.0f - __builtin_amdgcn_rcpf(I));
                    int kc = (int)__builtin_ceilf(l2 * -13.5134035f);
                    k = kc < 1 ? 1 : (kc > 15 ? 15 : kc);
                }
                kb[(size_t)(rbase + r) * H_SZ + c] = (unsigned char)k;
            }
        }
    }
}

// ---------------------------------------------------------------- K2: fused-loop bucket gather
// generic quad over runtime index (rare path)
#define GQUAD(IDX, BODY)                                                      \
    { const uint2 eq = *(const uint2*)&ent[IDX];                              \
      const unsigned sa = (unsigned)__builtin_amdgcn_readfirstlane((int)eq.x);\
      const unsigned sb = (unsigned)__builtin_amdgcn_readfirstlane((int)eq.y);\
      const uint2 qa = *(const uint2*)(W2cb + ((size_t)(sa & 0xffffu) << 10) + jc); \
      const uint2 qb = *(const uint2*)(W2cb + ((size_t)(sa >> 16) << 10) + jc);     \
      const uint2 qc = *(const uint2*)(W2cb + ((size_t)(sb & 0xffffu) << 10) + jc); \
      const uint2 qd = *(const uint2*)(W2cb + ((size_t)(sb >> 16) << 10) + jc);     \
      BODY }

#define TLOOP(K)                                                              \
    for (int i = stt[K]; i < stt[(K) + 1]; i += 4)                            \
        GQUAD(i, i2 += unp4(qa); i2 += unp4(qb); i2 += unp4(qc); i2 += unp4(qd);)

#define STEP                                                                  \
    { v2 = v2 * 0.95f + i2 * 0.05f;                                           \
      if (v2.x > 1.0f) { v2.x = 0.f; ++c0; }                                  \
      if (v2.y > 1.0f) { v2.y = 0.f; ++c1; }                                  \
      if (v2.z > 1.0f) { v2.z = 0.f; ++c2; }                                  \
      if (v2.w > 1.0f) { v2.w = 0.f; ++c3; } }

#define ADD4(GV) { GV += f0; GV += f1; GV += f2; GV += f3; }

__global__ __launch_bounds__(256, 4) void k2_snn(const unsigned char* __restrict__ kb,
                                                 const unsigned short* __restrict__ W2cb,
                                                 const float* __restrict__ b2,
                                                 const float* __restrict__ Wout,
                                                 const float* __restrict__ bout,
                                                 float* __restrict__ out) {
    const int b   = blockIdx.x;
    const int tid = threadIdx.x;
    const int jc  = tid * 4;

    __shared__ int cnt[16];
    __shared__ int curs[16];
    __shared__ int st[17];
    __shared__ unsigned short ent[1080];     // buckets padded to x4 + 1 sentinel quad
    __shared__ int flag;
    __shared__ int tot;
    __shared__ float rrow[H_SZ];

    if (tid < 16) { cnt[tid] = 0; if (tid == 0) { flag = 0; tot = 0; } }
    const unsigned int kw = *(const unsigned int*)(kb + (size_t)b * H_SZ + jc);
    const f32x4 b2q = *(const f32x4*)&b2[jc];
    __syncthreads();

    if (kw) {
        #pragma unroll
        for (int u = 0; u < 4; ++u) {
            const unsigned int ku = (kw >> (8 * u)) & 0xffu;
            if (ku) atomicAdd(&cnt[ku], 1);
        }
    }
    __syncthreads();
    if (tid == 0) {
        int s = 0;
        for (int k = 1; k <= 15; ++k) {
            st[k] = s; curs[k] = s;
            s += (cnt[k] + 3) & ~3;          // pad each bucket to multiple of 4
        }
        st[16] = s;
    }
    __syncthreads();
    if (kw) {
        #pragma unroll
        for (int u = 0; u < 4; ++u) {
            const unsigned int ku = (kw >> (8 * u)) & 0xffu;
            if (ku) {
                const int p = atomicAdd(&curs[ku], 1);
                ent[p] = (unsigned short)(jc + u);
            }
        }
    }
    if (tid >= 1 && tid < 16) {              // sentinel-pad the bucket tails
        for (int p = st[tid] + cnt[tid]; p < st[tid + 1]; ++p)
            ent[p] = (unsigned short)H_SZ;   // zero row of W2cb
    }
    if (tid < 4) ent[st[16] + tid] = (unsigned short)H_SZ;   // extra prefetch quad
    __syncthreads();

    int stt[17];
    #pragma unroll
    for (int k = 1; k <= 16; ++k) stt[k] = __builtin_amdgcn_readfirstlane(st[k]);

    // ---- fused gather: one loop over all quads, depth-1 rotate prefetch
    f32x4 G8 = {0,0,0,0}, G9 = {0,0,0,0}, G10 = {0,0,0,0}, G11 = {0,0,0,0};
    f32x4 G12 = {0,0,0,0}, G13 = {0,0,0,0}, G14 = {0,0,0,0}, G15 = {0,0,0,0};
    f32x4 Ps = {0,0,0,0};
    const int QT = stt[16] >> 2;

    uint2 eq = *(const uint2*)&ent[0];
    unsigned sa = (unsigned)__builtin_amdgcn_readfirstlane((int)eq.x);
    unsigned sb = (unsigned)__builtin_amdgcn_readfirstlane((int)eq.y);
    uint2 w0 = *(const uint2*)(W2cb + ((size_t)(sa & 0xffffu) << 10) + jc);
    uint2 w1 = *(const uint2*)(W2cb + ((size_t)(sa >> 16) << 10) + jc);
    uint2 w2 = *(const uint2*)(W2cb + ((size_t)(sb & 0xffffu) << 10) + jc);
    uint2 w3 = *(const uint2*)(W2cb + ((size_t)(sb >> 16) << 10) + jc);

    #pragma unroll 2
    for (int q = 0; q < QT; ++q) {
        // prefetch quad q+1 (extra sentinel quad guarantees it exists)
        const uint2 eqn = *(const uint2*)&ent[4 * (q + 1)];
        const unsigned san = (unsigned)__builtin_amdgcn_readfirstlane((int)eqn.x);
        const unsigned sbn = (unsigned)__builtin_amdgcn_readfirstlane((int)eqn.y);
        const uint2 n0 = *(const uint2*)(W2cb + ((size_t)(san & 0xffffu) << 10) + jc);
        const uint2 n1 = *(const uint2*)(W2cb + ((size_t)(san >> 16) << 10) + jc);
        const uint2 n2 = *(const uint2*)(W2cb + ((size_t)(sbn & 0xffffu) << 10) + jc);
        const uint2 n3 = *(const uint2*)(W2cb + ((size_t)(sbn >> 16) << 10) + jc);

        // consume quad q; target chosen by wave-uniform scalar branch tree
        const f32x4 f0 = unp4(w0), f1 = unp4(w1), f2 = unp4(w2), f3 = unp4(w3);
        const int x = q << 2;
        if (x >= stt[8]) {
            if (x >= stt[12]) {
                if (x >= stt[14]) { if (x >= stt[15]) ADD4(G15) else ADD4(G14) }
                else              { if (x >= stt[13]) ADD4(G13) else ADD4(G12) }
            } else {
                if (x >= stt[10]) { if (x >= stt[11]) ADD4(G11) else ADD4(G10) }
                else              { if (x >= stt[9])  ADD4(G9)  else ADD4(G8)  }
            }
        } else {
            Ps += relu4(f0); Ps += relu4(f1); Ps += relu4(f2); Ps += relu4(f3);
        }
        w0 = n0; w1 = n1; w2 = n2; w3 = n3;
    }

    // ---- certificate: M = b2 + Ps + relu(max G8..15) >= max_t I2_t
    f32x4 gm = vmax4(G8, G9);
    gm = vmax4(gm, G10); gm = vmax4(gm, G11); gm = vmax4(gm, G12);
    gm = vmax4(gm, G13); gm = vmax4(gm, G14); gm = vmax4(gm, G15);
    const float M0 = b2q.x + Ps.x + fmaxf(gm.x, 0.f);
    const float M1 = b2q.y + Ps.y + fmaxf(gm.y, 0.f);
    const float M2 = b2q.z + Ps.z + fmaxf(gm.z, 0.f);
    const float M3 = b2q.w + Ps.w + fmaxf(gm.w, 0.f);
    if ((M0 > SKIP_THR) || (M1 > SKIP_THR) || (M2 > SKIP_THR) || (M3 > SKIP_THR))
        atomicOr(&flag, 1);
    __syncthreads();

    if (flag == 0) {                         // proven spike-free: out = bout (bit-exact)
        if (tid < D_OUT) out[(size_t)b * D_OUT + tid] = bout[tid];
        return;
    }

    // ---- rare exact path: per-step re-gather from sorted buckets (static divisors)
    f32x4 v2 = {0,0,0,0};
    int c0 = 0, c1 = 0, c2 = 0, c3 = 0;
    { f32x4 i2 = b2q; TLOOP(1) STEP }                                     // t=1
    { f32x4 i2 = b2q; TLOOP(1) TLOOP(2) STEP }                            // t=2
    { f32x4 i2 = b2q; TLOOP(1) TLOOP(3) STEP }                            // t=3
    { f32x4 i2 = b2q; TLOOP(1) TLOOP(2) TLOOP(4) STEP }                   // t=4
    { f32x4 i2 = b2q; TLOOP(1) TLOOP(5) STEP }                            // t=5
    { f32x4 i2 = b2q; TLOOP(1) TLOOP(2) TLOOP(3) TLOOP(6) STEP }          // t=6
    { f32x4 i2 = b2q; TLOOP(1) TLOOP(7) STEP }                            // t=7
    { f32x4 i2 = b2q; TLOOP(1) TLOOP(2) TLOOP(4) TLOOP(8) STEP }          // t=8
    { f32x4 i2 = b2q; TLOOP(1) TLOOP(3) TLOOP(9) STEP }                   // t=9
    { f32x4 i2 = b2q; TLOOP(1) TLOOP(2) TLOOP(5) TLOOP(10) STEP }         // t=10
    { f32x4 i2 = b2q; TLOOP(1) TLOOP(11) STEP }                           // t=11
    { f32x4 i2 = b2q; TLOOP(1) TLOOP(2) TLOOP(3) TLOOP(4) TLOOP(6) TLOOP(12) STEP } // t=12
    { f32x4 i2 = b2q; TLOOP(1) TLOOP(13) STEP }                           // t=13
    { f32x4 i2 = b2q; TLOOP(1) TLOOP(2) TLOOP(7) TLOOP(14) STEP }         // t=14
    { f32x4 i2 = b2q; TLOOP(1) TLOOP(3) TLOOP(5) TLOOP(15) STEP }         // t=15

    const int my = c0 + c1 + c2 + c3;
    if (my) atomicAdd(&tot, my);
    __syncthreads();

    if (tot == 0) {                          // simulated exactly, no s2 spikes
        if (tid < D_OUT) out[(size_t)b * D_OUT + tid] = bout[tid];
        return;
    }

    rrow[jc + 0] = (float)c0 / 15.0f;
    rrow[jc + 1] = (float)c1 / 15.0f;
    rrow[jc + 2] = (float)c2 / 15.0f;
    rrow[jc + 3] = (float)c3 / 15.0f;
    __syncthreads();
    if (tid < D_OUT) {
        float a = bout[tid];
        const float* wrow = Wout + (size_t)tid * H_SZ;
        for (int j = 0; j < H_SZ; ++j) a = fmaf(rrow[j], wrow[j], a);
        out[(size_t)b * D_OUT + tid] = a;
    }
}

// ---------------------------------------------------------------- launch
extern "C" void kernel_launch(void* const* d_in, const int* in_sizes, int n_in,
                              void* d_out, int out_size, void* d_ws, size_t ws_size,
                              hipStream_t stream) {
    const float* x    = (const float*)d_in[0];
    const float* W1   = (const float*)d_in[1];
    const float* b1   = (const float*)d_in[2];
    const float* W2   = (const float*)d_in[3];
    const float* b2   = (const float*)d_in[4];
    const float* Wout = (const float*)d_in[5];
    const float* bout = (const float*)d_in[6];
    float* out = (float*)d_out;

    char* ws = (char*)d_ws;
    unsigned short* W2cb = (unsigned short*)(ws);              // 2 MB + 2 KB pad row
    unsigned char*  kbuf = (unsigned char*)(ws + (8 << 20));   // 8 MB intervals

    k0_transpose<<<dim3(H_SZ / 32, H_SZ / 32), dim3(32, 8), 0, stream>>>(W2, W2cb);
    k1_mfma<<<dim3(B_SZ / 128, H_SZ / 128), 256, 0, stream>>>(x, W1, b1, kbuf);
    k2_snn<<<B_SZ, 256, 0, stream>>>(kbuf, W2cb, b2, Wout, bout, out);
}

// Round 13
// 90.787 us; speedup vs baseline: 1.0394x; 1.0394x over previous
//
#include <hip/hip_runtime.h>
#include <hip/hip_bf16.h>

// SpikingPolicyNet: B=8192, D_in=256, H=1024, D_out=64, T=15, TAU=20, V_TH=1
//
// Pipeline:
//  K0 : W2 -> W2cb (bf16 W2^T, row 1024 zeroed = sentinel for padded entries)
//  K1 : bf16-MFMA x@W1.T; epilogue folds b1 and emits the closed-form spike
//       interval k = ceil(log2(1-1/I)/log2(0.95)) as byte plane kb[b][j]
//       (layer-1 spikes at t = k,2k,...; I1 time-invariant).
//  K2 : block-per-row. LDS bucket-sort by k, then a TRANSPOSED big-k view
//       ent2[r][c] (c = bucket 8+c, sentinel-padded): one broadcast
//       ds_read_b128 per row r yields one entry per bucket -> 8 loads ->
//       8 STATIC adds G8..G15 (no per-quad target selection; nothing for
//       the compiler to if-convert). Small-k (k<=7, ~0.5 spikers/row) is one
//       flat loop into a single relu-sum Ps.
//       Certificate: M = b2 + Ps + relu(max G8..15) >= max_t I2_t
//       (t<=7: I2 <= b2+Ps; t>=8: t's only divisor >=8 is t). M<=0.999
//       (margin >> fp drift) + induction v2_t <= M(1-.95^t) proves zero s2
//       spikes -> out = bout bit-exact (absmax==0 R1-R12 incl fp32 R1).
//       Bucket>32 overflow (P~1e-9) or cert failure -> exact per-step
//       re-gather from the complete flat list (always correct).

#define B_SZ   8192
#define D_IN   256
#define H_SZ   1024
#define D_OUT  64
#define T_STEPS 15
#define SKIP_THR 0.999f

typedef __attribute__((ext_vector_type(8))) short short8;
typedef __attribute__((ext_vector_type(4))) float f32x4;

static __device__ __forceinline__ unsigned int pk_bf16(float lo, float hi) {
    return (__builtin_bit_cast(unsigned int, hi) & 0xffff0000u) |
           (__builtin_bit_cast(unsigned int, lo) >> 16);
}
static __device__ __forceinline__ f32x4 unp4(uint2 w) {
    f32x4 r;
    r.x = __builtin_bit_cast(float, w.x << 16);
    r.y = __builtin_bit_cast(float, w.x & 0xffff0000u);
    r.z = __builtin_bit_cast(float, w.y << 16);
    r.w = __builtin_bit_cast(float, w.y & 0xffff0000u);
    return r;
}
static __device__ __forceinline__ f32x4 relu4(f32x4 a) {
    a.x = fmaxf(a.x, 0.f); a.y = fmaxf(a.y, 0.f);
    a.z = fmaxf(a.z, 0.f); a.w = fmaxf(a.w, 0.f);
    return a;
}
static __device__ __forceinline__ f32x4 vmax4(f32x4 a, f32x4 b) {
    f32x4 r;
    r.x = fmaxf(a.x, b.x); r.y = fmaxf(a.y, b.y);
    r.z = fmaxf(a.z, b.z); r.w = fmaxf(a.w, b.w);
    return r;
}

// ---------------------------------------------------------------- K0: W2 -> W2cb (+zero pad row)
__global__ __launch_bounds__(256) void k0_transpose(const float* __restrict__ W2,
                                                    unsigned short* __restrict__ W2cb) {
    __shared__ float tile[32][33];
    const int bx = blockIdx.x * 32;
    const int by = blockIdx.y * 32;
    const int tx = threadIdx.x;
    const int ty = threadIdx.y;
    #pragma unroll
    for (int i = ty; i < 32; i += 8)
        tile[i][tx] = W2[(by + i) * H_SZ + bx + tx];
    __syncthreads();
    #pragma unroll
    for (int i = ty; i < 32; i += 8)
        W2cb[(size_t)(bx + i) * H_SZ + by + tx] =
            (unsigned short)(__builtin_bit_cast(unsigned int, tile[tx][i]) >> 16);
    if (blockIdx.x == 0 && blockIdx.y == 0) {                   // zero sentinel row 1024
        const int t = ty * 32 + tx;
        #pragma unroll
        for (int i = 0; i < 4; ++i)
            W2cb[(size_t)H_SZ * H_SZ + i * 256 + t] = 0;
    }
}

// ---------------------------------------------------------------- K1: interval byte-plane from x@W1.T+b1
__global__ __launch_bounds__(256) void k1_mfma(const float* __restrict__ A,
                                               const float* __restrict__ Bw,
                                               const float* __restrict__ b1,
                                               unsigned char* __restrict__ kb) {
    __shared__ unsigned int As4[2048];   // 128 rows x 32 bf16, 16B-chunk XOR swizzle
    __shared__ unsigned int Bs4[2048];
    const int tid  = threadIdx.x;
    const int m0   = blockIdx.x * 128;
    const int n0   = blockIdx.y * 128;
    const int lane = tid & 63;
    const int wid  = tid >> 6;
    const int wr   = wid >> 1, wc = wid & 1;

    const int row0 = tid >> 2;
    const int row1 = row0 + 64;
    const int q0   = tid & 3;

    f32x4 acc[4][4] = {};
    float4 s0[8], s1[8];

    auto LOAD = [&](float4* s, int kbk) {
        const float* pa0 = A  + (m0 + row0) * D_IN + kbk + q0 * 8;
        const float* pa1 = A  + (m0 + row1) * D_IN + kbk + q0 * 8;
        const float* pb0 = Bw + (n0 + row0) * D_IN + kbk + q0 * 8;
        const float* pb1 = Bw + (n0 + row1) * D_IN + kbk + q0 * 8;
        s[0] = *(const float4*)pa0; s[1] = *(const float4*)(pa0 + 4);
        s[2] = *(const float4*)pa1; s[3] = *(const float4*)(pa1 + 4);
        s[4] = *(const float4*)pb0; s[5] = *(const float4*)(pb0 + 4);
        s[6] = *(const float4*)pb1; s[7] = *(const float4*)(pb1 + 4);
    };
    auto WRITE = [&](const float4* s) {
        const int i0 = row0 * 16 + (q0 ^ ((row0 >> 1) & 3)) * 4;
        const int i1 = row1 * 16 + (q0 ^ ((row1 >> 1) & 3)) * 4;
        *(uint4*)&As4[i0] = make_uint4(pk_bf16(s[0].x, s[0].y), pk_bf16(s[0].z, s[0].w),
                                       pk_bf16(s[1].x, s[1].y), pk_bf16(s[1].z, s[1].w));
        *(uint4*)&As4[i1] = make_uint4(pk_bf16(s[2].x, s[2].y), pk_bf16(s[2].z, s[2].w),
                                       pk_bf16(s[3].x, s[3].y), pk_bf16(s[3].z, s[3].w));
        *(uint4*)&Bs4[i0] = make_uint4(pk_bf16(s[4].x, s[4].y), pk_bf16(s[4].z, s[4].w),
                                       pk_bf16(s[5].x, s[5].y), pk_bf16(s[5].z, s[5].w));
        *(uint4*)&Bs4[i1] = make_uint4(pk_bf16(s[6].x, s[6].y), pk_bf16(s[6].z, s[6].w),
                                       pk_bf16(s[7].x, s[7].y), pk_bf16(s[7].z, s[7].w));
    };
    auto COMPUTE = [&]() {
        short8 afr[4], bfr[4];
        const int q  = lane >> 4;
        const int lr = lane & 15;
        #pragma unroll
        for (int mf = 0; mf < 4; ++mf) {
            const int ra = wr * 64 + mf * 16 + lr;
            afr[mf] = *(const short8*)&As4[ra * 16 + (q ^ ((ra >> 1) & 3)) * 4];
            const int rb = wc * 64 + mf * 16 + lr;
            bfr[mf] = *(const short8*)&Bs4[rb * 16 + (q ^ ((rb >> 1) & 3)) * 4];
        }
        #pragma unroll
        for (int mf = 0; mf < 4; ++mf)
            #pragma unroll
            for (int nf = 0; nf < 4; ++nf)
                acc[mf][nf] = __builtin_amdgcn_mfma_f32_16x16x32_bf16(
                    afr[mf], bfr[nf], acc[mf][nf], 0, 0, 0);
    };

    LOAD(s0, 0);
    for (int kk = 0; kk < D_IN; kk += 64) {
        if (kk + 32 < D_IN) LOAD(s1, kk + 32);
        __syncthreads();
        WRITE(s0);
        __syncthreads();
        COMPUTE();
        if (kk + 64 < D_IN) LOAD(s0, kk + 64);
        __syncthreads();
        WRITE(s1);
        __syncthreads();
        COMPUTE();
    }

    // Epilogue: I = acc + b1[col]; k = ceil(log2(1-1/I)*-13.5134035), 0 = none.
    const int lr = lane & 15;
    const int qq = lane >> 4;
    float b1v[4];
    #pragma unroll
    for (int nf = 0; nf < 4; ++nf) b1v[nf] = b1[n0 + wc * 64 + nf * 16 + lr];

    #pragma unroll
    for (int mf = 0; mf < 4; ++mf) {
        const int rbase = m0 + wr * 64 + mf * 16 + qq * 4;
        #pragma unroll
        for (int nf = 0; nf < 4; ++nf) {
            const int c = n0 + wc * 64 + nf * 16 + lr;
            #pragma unroll
            for (int r = 0; r < 4; ++r) {
                const float I = acc[mf][nf][r] + b1v[nf];
                int k = 0;
                if (I > 1.8632055f) {
                    const float l2 = __builtin_amdgcn_logf(1.0f - __builtin_amdgcn_rcpf(I));
                    int kc = (int)__builtin_ceilf(l2 * -13.5134035f);
                    k = kc < 1 ? 1 : (kc > 15 ? 15 : kc);
                }
                kb[(size_t)(rbase + r) * H_SZ + c] = (unsigned char)k;
            }
        }
    }
}

// ---------------------------------------------------------------- K2: transposed-bucket gather
#define GQUAD(IDX, BODY)                                                      \
    { const uint2 eq = *(const uint2*)&ent[IDX];                              \
      const unsigned sa = (unsigned)__builtin_amdgcn_readfirstlane((int)eq.x);\
      const unsigned sb = (unsigned)__builtin_amdgcn_readfirstlane((int)eq.y);\
      const uint2 qa = *(const uint2*)(W2cb + ((size_t)(sa & 0xffffu) << 10) + jc); \
      const uint2 qb = *(const uint2*)(W2cb + ((size_t)(sa >> 16) << 10) + jc);     \
      const uint2 qc = *(const uint2*)(W2cb + ((size_t)(sb & 0xffffu) << 10) + jc); \
      const uint2 qd = *(const uint2*)(W2cb + ((size_t)(sb >> 16) << 10) + jc);     \
      BODY }

#define TLOOP(K)                                                              \
    for (int i = stt[K]; i < stt[(K) + 1]; i += 4)                            \
        GQUAD(i, i2 += unp4(qa); i2 += unp4(qb); i2 += unp4(qc); i2 += unp4(qd);)

#define STEP                                                                  \
    { v2 = v2 * 0.95f + i2 * 0.05f;                                           \
      if (v2.x > 1.0f) { v2.x = 0.f; ++c0; }                                  \
      if (v2.y > 1.0f) { v2.y = 0.f; ++c1; }                                  \
      if (v2.z > 1.0f) { v2.z = 0.f; ++c2; }                                  \
      if (v2.w > 1.0f) { v2.w = 0.f; ++c3; } }

__global__ __launch_bounds__(256, 4) void k2_snn(const unsigned char* __restrict__ kb,
                                                 const unsigned short* __restrict__ W2cb,
                                                 const float* __restrict__ b2,
                                                 const float* __restrict__ Wout,
                                                 const float* __restrict__ bout,
                                                 float* __restrict__ out) {
    const int b   = blockIdx.x;
    const int tid = threadIdx.x;
    const int jc  = tid * 4;

    __shared__ int cnt[16];
    __shared__ int curs[16];
    __shared__ int st[17];
    __shared__ __align__(16) unsigned short ent[1088];   // flat bucketed list (complete)
    __shared__ uint4 ent2q[32];                           // transposed big-k view [32][8] u16
    __shared__ int flag;
    __shared__ int tot;
    __shared__ int maxb;
    __shared__ float rrow[H_SZ];

    if (tid < 16) { cnt[tid] = 0; if (tid == 0) { flag = 0; tot = 0; maxb = 0; } }
    const unsigned int kw = *(const unsigned int*)(kb + (size_t)b * H_SZ + jc);
    const f32x4 b2q = *(const f32x4*)&b2[jc];
    __syncthreads();

    if (kw) {
        #pragma unroll
        for (int u = 0; u < 4; ++u) {
            const unsigned int ku = (kw >> (8 * u)) & 0xffu;
            if (ku) atomicAdd(&cnt[ku], 1);
        }
    }
    __syncthreads();

    if (tid >= 1 && tid <= 16) {             // parallel prefix over buckets
        int s = 0;
        for (int k = 1; k < tid; ++k) s += (cnt[k] + 3) & ~3;
        st[tid] = s;
        if (tid < 16) curs[tid] = s;
    }
    if (tid < 8) atomicMax(&maxb, cnt[8 + tid]);
    __syncthreads();

    if (kw) {
        #pragma unroll
        for (int u = 0; u < 4; ++u) {
            const unsigned int ku = (kw >> (8 * u)) & 0xffu;
            if (ku) {
                const int p = atomicAdd(&curs[ku], 1);
                ent[p] = (unsigned short)(jc + u);
            }
        }
    }
    if (tid >= 1 && tid < 16) {              // sentinel-pad the flat bucket tails
        for (int p = st[tid] + cnt[tid]; p < st[tid + 1]; ++p)
            ent[p] = (unsigned short)H_SZ;
    }
    __syncthreads();

    {   // transposed big-k view: ent2[r][c] = r-th entry of bucket 8+c (or sentinel)
        const int r = tid >> 3, c = tid & 7;
        unsigned short e = (unsigned short)H_SZ;
        if (r < cnt[8 + c]) e = ent[st[8 + c] + r];
        ((unsigned short*)ent2q)[tid] = e;
    }
    __syncthreads();

    int stt[17];
    #pragma unroll
    for (int k = 1; k <= 16; ++k) stt[k] = __builtin_amdgcn_readfirstlane(st[k]);
    const int mb0 = __builtin_amdgcn_readfirstlane(maxb);
    const int mb  = mb0 > 32 ? 32 : mb0;

    // ---- small-k (k<=7): single flat loop, single relu-sum target
    f32x4 Ps = {0,0,0,0};
    for (int i = 0; i < stt[8]; i += 4)
        GQUAD(i, Ps += relu4(unp4(qa)); Ps += relu4(unp4(qb));
                 Ps += relu4(unp4(qc)); Ps += relu4(unp4(qd));)

    // ---- big-k: transposed loop, one entry per bucket per row, static targets
    f32x4 G8 = {0,0,0,0}, G9 = {0,0,0,0}, G10 = {0,0,0,0}, G11 = {0,0,0,0};
    f32x4 G12 = {0,0,0,0}, G13 = {0,0,0,0}, G14 = {0,0,0,0}, G15 = {0,0,0,0};
    #pragma unroll 2
    for (int r = 0; r < mb; ++r) {
        const uint4 e = ent2q[r];            // broadcast ds_read_b128
        const unsigned ex = (unsigned)__builtin_amdgcn_readfirstlane((int)e.x);
        const unsigned ey = (unsigned)__builtin_amdgcn_readfirstlane((int)e.y);
        const unsigned ez = (unsigned)__builtin_amdgcn_readfirstlane((int)e.z);
        const unsigned ew = (unsigned)__builtin_amdgcn_readfirstlane((int)e.w);
        const uint2 w0 = *(const uint2*)(W2cb + ((size_t)(ex & 0xffffu) << 10) + jc);
        const uint2 w1 = *(const uint2*)(W2cb + ((size_t)(ex >> 16) << 10) + jc);
        const uint2 w2 = *(const uint2*)(W2cb + ((size_t)(ey & 0xffffu) << 10) + jc);
        const uint2 w3 = *(const uint2*)(W2cb + ((size_t)(ey >> 16) << 10) + jc);
        const uint2 w4 = *(const uint2*)(W2cb + ((size_t)(ez & 0xffffu) << 10) + jc);
        const uint2 w5 = *(const uint2*)(W2cb + ((size_t)(ez >> 16) << 10) + jc);
        const uint2 w6 = *(const uint2*)(W2cb + ((size_t)(ew & 0xffffu) << 10) + jc);
        const uint2 w7 = *(const uint2*)(W2cb + ((size_t)(ew >> 16) << 10) + jc);
        G8  += unp4(w0); G9  += unp4(w1); G10 += unp4(w2); G11 += unp4(w3);
        G12 += unp4(w4); G13 += unp4(w5); G14 += unp4(w6); G15 += unp4(w7);
    }

    // ---- certificate: M = b2 + Ps + relu(max G8..15) >= max_t I2_t
    f32x4 gm = vmax4(G8, G9);
    gm = vmax4(gm, G10); gm = vmax4(gm, G11); gm = vmax4(gm, G12);
    gm = vmax4(gm, G13); gm = vmax4(gm, G14); gm = vmax4(gm, G15);
    const float M0 = b2q.x + Ps.x + fmaxf(gm.x, 0.f);
    const float M1 = b2q.y + Ps.y + fmaxf(gm.y, 0.f);
    const float M2 = b2q.z + Ps.z + fmaxf(gm.z, 0.f);
    const float M3 = b2q.w + Ps.w + fmaxf(gm.w, 0.f);
    if ((M0 > SKIP_THR) || (M1 > SKIP_THR) || (M2 > SKIP_THR) || (M3 > SKIP_THR))
        atomicOr(&flag, 1);
    if (tid == 0 && mb0 > 32) atomicOr(&flag, 1);   // cert incomplete -> exact path
    __syncthreads();

    if (flag == 0) {                         // proven spike-free: out = bout (bit-exact)
        if (tid < D_OUT) out[(size_t)b * D_OUT + tid] = bout[tid];
        return;
    }

    // ---- rare exact path: per-step re-gather from flat buckets (static divisors)
    f32x4 v2 = {0,0,0,0};
    int c0 = 0, c1 = 0, c2 = 0, c3 = 0;
    { f32x4 i2 = b2q; TLOOP(1) STEP }                                     // t=1
    { f32x4 i2 = b2q; TLOOP(1) TLOOP(2) STEP }                            // t=2
    { f32x4 i2 = b2q; TLOOP(1) TLOOP(3) STEP }                            // t=3
    { f32x4 i2 = b2q; TLOOP(1) TLOOP(2) TLOOP(4) STEP }                   // t=4
    { f32x4 i2 = b2q; TLOOP(1) TLOOP(5) STEP }                            // t=5
    { f32x4 i2 = b2q; TLOOP(1) TLOOP(2) TLOOP(3) TLOOP(6) STEP }          // t=6
    { f32x4 i2 = b2q; TLOOP(1) TLOOP(7) STEP }                            // t=7
    { f32x4 i2 = b2q; TLOOP(1) TLOOP(2) TLOOP(4) TLOOP(8) STEP }          // t=8
    { f32x4 i2 = b2q; TLOOP(1) TLOOP(3) TLOOP(9) STEP }                   // t=9
    { f32x4 i2 = b2q; TLOOP(1) TLOOP(2) TLOOP(5) TLOOP(10) STEP }         // t=10
    { f32x4 i2 = b2q; TLOOP(1) TLOOP(11) STEP }                           // t=11
    { f32x4 i2 = b2q; TLOOP(1) TLOOP(2) TLOOP(3) TLOOP(4) TLOOP(6) TLOOP(12) STEP } // t=12
    { f32x4 i2 = b2q; TLOOP(1) TLOOP(13) STEP }                           // t=13
    { f32x4 i2 = b2q; TLOOP(1) TLOOP(2) TLOOP(7) TLOOP(14) STEP }         // t=14
    { f32x4 i2 = b2q; TLOOP(1) TLOOP(3) TLOOP(5) TLOOP(15) STEP }         // t=15

    const int my = c0 + c1 + c2 + c3;
    if (my) atomicAdd(&tot, my);
    __syncthreads();

    if (tot == 0) {                          // simulated exactly, no s2 spikes
        if (tid < D_OUT) out[(size_t)b * D_OUT + tid] = bout[tid];
        return;
    }

    rrow[jc + 0] = (float)c0 / 15.0f;
    rrow[jc + 1] = (float)c1 / 15.0f;
    rrow[jc + 2] = (float)c2 / 15.0f;
    rrow[jc + 3] = (float)c3 / 15.0f;
    __syncthreads();
    if (tid < D_OUT) {
        float a = bout[tid];
        const float* wrow = Wout + (size_t)tid * H_SZ;
        for (int j = 0; j < H_SZ; ++j) a = fmaf(rrow[j], wrow[j], a);
        out[(size_t)b * D_OUT + tid] = a;
    }
}

// ---------------------------------------------------------------- launch
extern "C" void kernel_launch(void* const* d_in, const int* in_sizes, int n_in,
                              void* d_out, int out_size, void* d_ws, size_t ws_size,
                              hipStream_t stream) {
    const float* x    = (const float*)d_in[0];
    const float* W1   = (const float*)d_in[1];
    const float* b1   = (const float*)d_in[2];
    const float* W2   = (const float*)d_in[3];
    const float* b2   = (const float*)d_in[4];
    const float* Wout = (const float*)d_in[5];
    const float* bout = (const float*)d_in[6];
    float* out = (float*)d_out;

    char* ws = (char*)d_ws;
    unsigned short* W2cb = (unsigned short*)(ws);              // 2 MB + 2 KB pad row
    unsigned char*  kbuf = (unsigned char*)(ws + (8 << 20));   // 8 MB intervals

    k0_transpose<<<dim3(H_SZ / 32, H_SZ / 32), dim3(32, 8), 0, stream>>>(W2, W2cb);
    k1_mfma<<<dim3(B_SZ / 128, H_SZ / 128), 256, 0, stream>>>(x, W1, b1, kbuf);
    k2_snn<<<B_SZ, 256, 0, stream>>>(kbuf, W2cb, b2, Wout, bout, out);
}